// Round 1
// 981.664 us; speedup vs baseline: 1.2045x; 1.2045x over previous
//
#include <hip/hip_runtime.h>

#define LB 50
#define NITEMS 249999

__device__ __forceinline__ float sigm(float x){ return 1.0f/(1.0f + __expf(-x)); }

__device__ __forceinline__ unsigned int pack2(float x, float y){
  unsigned int a = __float_as_uint(x), b = __float_as_uint(y);
  a = (a + 0x7fffu + ((a>>16)&1u)) >> 16;   // RNE fp32->bf16
  b = (b + 0x7fffu + ((b>>16)&1u)) >> 16;
  return a | (b<<16);
}

__device__ __forceinline__ unsigned short bf16of(float x){
  unsigned int a = __float_as_uint(x);
  a = (a + 0x7fffu + ((a>>16)&1u)) >> 16;
  return (unsigned short)a;
}

// ---------- pos_part[l][h] = pos_w[l] @ w1[0:128] ----------
__global__ void k_pos_part(const float* __restrict__ pos_w, const float* __restrict__ w1,
                           float* __restrict__ pos_part){
  int l = blockIdx.x, h = threadIdx.x;
  __shared__ float pr[128];
  pr[h] = pos_w[l*128 + h];
  __syncthreads();
  float s = 0.f;
  for (int j = 0; j < 128; ++j) s += pr[j] * w1[j*128 + h];
  pos_part[l*128 + h] = s;
}

// ---------- per-batch: hs (masked mean), lasts concat, ht0 ----------
__global__ void k_batch_prep(const float* __restrict__ hidden, const int* __restrict__ mask,
                             float* __restrict__ hs, float* __restrict__ lastsc,
                             float* __restrict__ ht0v){
  int b = blockIdx.x, h = threadIdx.x;
  const float* hb = hidden + (size_t)b*LB*128;
  const int* mb = mask + b*LB;
  int len = 0; float msum = 0.f, acc = 0.f;
  for (int l = 0; l < LB; ++l){
    int mi = mb[l];
    float mf = (float)mi;
    len += mi;
    msum += mf;
    acc += hb[l*128 + h] * mf;
  }
  hs[b*128+h] = acc / msum;
  for (int j = 0; j < 3; ++j){
    int idx = len - 1 - j;
    if (idx < -1) idx = -1;
    if (idx < 0) idx += LB;
    lastsc[b*384 + j*128 + h] = hb[idx*128 + h];
  }
  int i0 = len - 1; if (i0 < 0) i0 += LB;
  ht0v[b*128+h] = hb[i0*128 + h];
}

// ---------- tiled fp32 GEMM over 25600x128 rows, W is 128x128 ----------
// MODE 0: OUT[r][c] = tanh(acc + pos_part[r%50][c])
// MODE 1: beta[r]   = (sum_c sigmoid(acc + hsg[r/50][c]) * w2[c]) * mask[r]
// MODE 2: OUT[r][c] = acc + bias[c]
template<int MODE>
__global__ __launch_bounds__(256) void k_gemmA(const float* __restrict__ IN,
      const float* __restrict__ W, const float* __restrict__ extra,
      const float* __restrict__ w2, const int* __restrict__ mask,
      float* __restrict__ OUT){
  __shared__ float hidL[64*129];
  __shared__ float red[64*17];
  int t = threadIdx.x;
  int r0 = blockIdx.x * 64;
  for (int i = 0; i < 32; ++i){
    int p = i*256 + t;
    int row = p >> 7, k = p & 127;
    hidL[row*129 + k] = IN[(size_t)(r0+row)*128 + k];
  }
  __syncthreads();
  int tx = t & 15, ty = t >> 4;
  float acc[4][8];
#pragma unroll
  for (int m=0;m<4;++m)
#pragma unroll
    for (int c=0;c<8;++c) acc[m][c]=0.f;
  for (int k = 0; k < 128; ++k){
    float4 wa = *(const float4*)&W[k*128 + tx*4];
    float4 wb = *(const float4*)&W[k*128 + 64 + tx*4];
#pragma unroll
    for (int m = 0; m < 4; ++m){
      float a = hidL[(ty*4+m)*129 + k];
      acc[m][0] += a*wa.x; acc[m][1] += a*wa.y; acc[m][2] += a*wa.z; acc[m][3] += a*wa.w;
      acc[m][4] += a*wb.x; acc[m][5] += a*wb.y; acc[m][6] += a*wb.z; acc[m][7] += a*wb.w;
    }
  }
  if constexpr (MODE == 0){
#pragma unroll
    for (int m=0;m<4;++m){
      int r = r0 + ty*4 + m; int l = r % 50;
#pragma unroll
      for (int ci=0;ci<4;++ci){
        int c = tx*4+ci;
        OUT[(size_t)r*128 + c] = tanhf(acc[m][ci] + extra[l*128+c]);
        c = 64 + tx*4 + ci;
        OUT[(size_t)r*128 + c] = tanhf(acc[m][4+ci] + extra[l*128+c]);
      }
    }
  } else if constexpr (MODE == 1){
#pragma unroll
    for (int m=0;m<4;++m){
      int r = r0 + ty*4 + m; int bb = r / 50;
      float part = 0.f;
#pragma unroll
      for (int ci=0;ci<4;++ci){
        int c = tx*4+ci;
        float s = sigm(acc[m][ci] + extra[bb*128+c]); part += s * w2[c];
        c = 64 + tx*4 + ci;
        s = sigm(acc[m][4+ci] + extra[bb*128+c]); part += s * w2[c];
      }
      red[(ty*4+m)*17 + tx] = part;
    }
    __syncthreads();
    if (t < 64){
      float s = 0.f;
      for (int x=0;x<16;++x) s += red[t*17+x];
      int r = r0 + t;
      OUT[r] = s * (float)mask[r];
    }
  } else {
#pragma unroll
    for (int m=0;m<4;++m){
      int r = r0 + ty*4 + m;
#pragma unroll
      for (int ci=0;ci<4;++ci){
        int c = tx*4+ci;
        OUT[(size_t)r*128 + c] = acc[m][ci] + extra[c];
        c = 64 + tx*4 + ci;
        OUT[(size_t)r*128 + c] = acc[m][4+ci] + extra[c];
      }
    }
  }
}

// ---------- hsg[b][h] = glu1_b[h] + hs[b] @ glu2_w ----------
__global__ void k_hsg(const float* __restrict__ hs, const float* __restrict__ glu2_w,
                      const float* __restrict__ glu1_b, float* __restrict__ hsg){
  int b = blockIdx.x, h = threadIdx.x;
  __shared__ float hl[128];
  hl[h] = hs[b*128+h];
  __syncthreads();
  float s = glu1_b[h];
  for (int j=0;j<128;++j) s += hl[j]*glu2_w[j*128+h];
  hsg[b*128+h] = s;
}

// ---------- select[b][h] = sum_l beta[b,l]*hidden[b,l,h] ----------
__global__ void k_select(const float* __restrict__ beta, const float* __restrict__ hidden,
                         float* __restrict__ sel){
  int b = blockIdx.x, h = threadIdx.x;
  float s = 0.f;
  for (int l=0;l<LB;++l) s += beta[b*LB+l]*hidden[((size_t)b*LB+l)*128 + h];
  sel[b*128+h] = s;
}

// ---------- hts (K-axis-normalized) then q0 = hts@wz + bz ----------
__global__ void k_hts_q0(const float* __restrict__ lastsc,
   const float* __restrict__ lq_w0, const float* __restrict__ lq_b0,
   const float* __restrict__ lq_w1, const float* __restrict__ lq_b1,
   const float* __restrict__ lq_w2, const float* __restrict__ lq_b2,
   const float* __restrict__ wz, const float* __restrict__ bz,
   float* __restrict__ q0f){
  int b = blockIdx.x, h = threadIdx.x;
  __shared__ float ll[384];
  __shared__ float htsL[384];
  for (int i=h;i<384;i+=128) ll[i]=lastsc[b*384+i];
  __syncthreads();
  float h0 = lq_b0[h], h1 = lq_b1[h], h2 = lq_b2[h];
  for (int j=0;j<128;++j) h0 += ll[j]*lq_w0[j*128+h];
  for (int j=0;j<256;++j) h1 += ll[j]*lq_w1[j*128+h];
  for (int j=0;j<384;++j) h2 += ll[j]*lq_w2[j*128+h];
  float nrm = sqrtf(h0*h0+h1*h1+h2*h2) + 1e-12f;
  htsL[h] = h0/nrm; htsL[128+h] = h1/nrm; htsL[256+h] = h2/nrm;
  __syncthreads();
  for (int k=0;k<3;++k){
    float s = bz[h];
    for (int j=0;j<128;++j) s += htsL[k*128+j]*wz[j*128+h];
    q0f[b*384 + k*128 + h] = s;
  }
}

// ---------- scrambled-reshape attention: q0xq1 -> 2 softmaxes -> ais ----------
__global__ __launch_bounds__(256) void k_attn(const float* __restrict__ q0f,
    const float* __restrict__ q1f, const float* __restrict__ q2f,
    const int* __restrict__ mask, float* __restrict__ ais){
  int b = blockIdx.x, t = threadIdx.x;
  __shared__ float q0L[384];
  __shared__ float q1L[6400];
  __shared__ float S[1200];
  __shared__ float A_[400];
  __shared__ float mkL[50];
  for (int i=t;i<384;i+=256) q0L[i]=q0f[b*384+i];
  for (int i=t;i<6400;i+=256) q1L[i]=q1f[(size_t)b*6400+i];
  if (t<50) mkL[t] = (float)mask[b*50+t];
  __syncthreads();
  // S[c][l] = 2*sigmoid(q0v[n,kk,:] . q1v[n,l,:]), flat-index semantics
  for (int idx=t; idx<1200; idx+=256){
    int c = idx/50, l = idx - c*50;
    int g = c/3, kk = c - g*3;
    const float* q0p = q0L + 48*g + 16*kk;
    const float* q1p = q1L + 800*g + 16*l;
    float d = 0.f;
#pragma unroll
    for (int dd=0;dd<16;++dd) d += q0p[dd]*q1p[dd];
    S[c*50+l] = 2.f*sigm(d);
  }
  __syncthreads();
  // softmax over l per c (unmasked)
  if (t < 24){
    float m = -1e30f;
    for (int l=0;l<50;++l) m = fmaxf(m, S[t*50+l]);
    float s = 0.f;
    for (int l=0;l<50;++l){ float e=__expf(S[t*50+l]-m); S[t*50+l]=e; s+=e; }
    float inv = 1.f/s;
    for (int l=0;l<50;++l) S[t*50+l] *= inv;
  }
  __syncthreads();
  // Lp-pool over kk, mask, second softmax over l per head g
  if (t < 8){
    int g = t;
    float m = -1e30f;
    for (int l=0;l<50;++l){
      float a0=S[(3*g+0)*50+l], a1=S[(3*g+1)*50+l], a2=S[(3*g+2)*50+l];
      float p = sqrtf(a0*a0+a1*a1+a2*a2);
      float v = (mkL[l] > 0.f) ? 2.f*p : -1e30f;
      A_[l*8+g]=v; m=fmaxf(m,v);
    }
    float s=0.f;
    for (int l=0;l<50;++l){ float e=__expf(A_[l*8+g]-m); A_[l*8+g]=e; s+=e; }
    float inv=1.f/s;
    for (int l=0;l<50;++l) A_[l*8+g]*=inv;
  }
  __syncthreads();
  if (t < 128){
    int h=t; float acc=0.f;
    for (int l=0;l<50;++l) acc += A_[l*8+(h>>4)] * q2f[((size_t)b*50+l)*128+h] * mkL[l];
    ais[b*128+h]=acc;
  }
}

// ---------- session = normalize(0.5*(select + [ais|ht0]@lt2_w + lt2_b)) ----------
// also emits bf16-packed session rows (RNE) for the MFMA output kernel
__global__ void k_session(const float* __restrict__ ais, const float* __restrict__ ht0v,
   const float* __restrict__ sel, const float* __restrict__ lt2_w, const float* __restrict__ lt2_b,
   float* __restrict__ session, unsigned short* __restrict__ sbf){
  int b = blockIdx.x, h = threadIdx.x;
  __shared__ float aL[128];
  __shared__ float hL[128];
  __shared__ float red[128];
  aL[h]=ais[b*128+h]; hL[h]=ht0v[b*128+h];
  __syncthreads();
  float a = lt2_b[h];
  for (int j=0;j<128;++j) a += aL[j]*lt2_w[j*128+h];
  for (int j=0;j<128;++j) a += hL[j]*lt2_w[(128+j)*128+h];
  float s = (sel[b*128+h] + a)*0.5f;
  red[h]=s*s; __syncthreads();
  for (int off=64; off>0; off>>=1){
    if (h<off) red[h]+=red[h+off];
    __syncthreads();
  }
  float v = s / (sqrtf(red[0]) + 1e-12f);
  session[b*128+h] = v;
  sbf[b*128+h] = bf16of(v);
}

// ---------- inv_norm[i] = 16/(||emb_w[1+i]||+1e-12) ----------
__global__ __launch_bounds__(256) void k_invnorm(const float* __restrict__ emb, float* __restrict__ invn){
  int t = threadIdx.x;
  int row = blockIdx.x*4 + (t>>6);
  int lane = t & 63;
  if (row >= NITEMS) return;
  float2 v = *(const float2*)&emb[(size_t)(1+row)*128 + lane*2];
  float ss = v.x*v.x + v.y*v.y;
  for (int off=32; off; off>>=1) ss += __shfl_down(ss, off, 64);
  if (lane==0) invn[row] = 16.f/(sqrtf(ss)+1e-12f);
}

// ---------- out[m][n] = session[m] . (16*normalized emb[1+n]) via bf16 MFMA ----------
// Operand-swapped layout: D' = E_tile . S_tile^T, so each lane owns 4 CONSECUTIVE n
// at one m -> 16B stores. E fragments (pre-scaled, bf16) persist in registers across
// the 4 m-tiles; S read directly from L2-resident bf16 copy. No LDS, no barriers.
typedef short bhalf8 __attribute__((ext_vector_type(8)));
typedef float f32x4 __attribute__((ext_vector_type(4)));

struct f4a { float x, y, z, w; };   // align(4): row stride N*4 is odd*4, only dword-aligned

__global__ __launch_bounds__(256) void k_out(const unsigned short* __restrict__ sbf,
    const float* __restrict__ emb, const float* __restrict__ invn, float* __restrict__ out){
  int t = threadIdx.x;
  int n0 = blockIdx.x * 128;
  int lane = t & 63, w = t >> 6;
  int r16 = lane & 15, quad = lane >> 4;

  // persistent E fragments: ef[ni2][kc], lane holds E[n0+w*32+ni2*16+r16][kc*32+quad*8 ..+7]
  bhalf8 ef[2][4];
#pragma unroll
  for (int ni2=0; ni2<2; ++ni2){
    int item = n0 + w*32 + ni2*16 + r16;
    float s = (item < NITEMS) ? invn[item] : 0.f;
    const float* ep = emb + (size_t)(1+item)*128 + quad*8;
#pragma unroll
    for (int kc=0; kc<4; ++kc){
      float4 v0 = {0.f,0.f,0.f,0.f}, v1 = {0.f,0.f,0.f,0.f};
      if (item < NITEMS){
        v0 = *(const float4*)(ep + kc*32);
        v1 = *(const float4*)(ep + kc*32 + 4);
      }
      union { bhalf8 h; unsigned int u[4]; } cv;
      cv.u[0] = pack2(v0.x*s, v0.y*s);
      cv.u[1] = pack2(v0.z*s, v0.w*s);
      cv.u[2] = pack2(v1.x*s, v1.y*s);
      cv.u[3] = pack2(v1.z*s, v1.w*s);
      ef[ni2][kc] = cv.h;
    }
  }

#pragma unroll
  for (int mb=0; mb<4; ++mb){
    f32x4 acc[2][8];
#pragma unroll
    for (int ni2=0; ni2<2; ++ni2)
#pragma unroll
      for (int mi=0; mi<8; ++mi) acc[ni2][mi] = (f32x4){0.f,0.f,0.f,0.f};

#pragma unroll
    for (int kc=0; kc<4; ++kc){
      bhalf8 bf[8];
#pragma unroll
      for (int mi=0; mi<8; ++mi)
        bf[mi] = *(const bhalf8*)&sbf[(size_t)(mb*128 + mi*16 + r16)*128 + kc*32 + quad*8];
#pragma unroll
      for (int mi=0; mi<8; ++mi){
        acc[0][mi] = __builtin_amdgcn_mfma_f32_16x16x32_bf16(ef[0][kc], bf[mi], acc[0][mi], 0,0,0);
        acc[1][mi] = __builtin_amdgcn_mfma_f32_16x16x32_bf16(ef[1][kc], bf[mi], acc[1][mi], 0,0,0);
      }
    }

    // lane stores out[m][n..n+3]: m = mb*128+mi*16+r16, n = n0+w*32+ni2*16+quad*4
#pragma unroll
    for (int ni2=0; ni2<2; ++ni2){
      int n = n0 + w*32 + ni2*16 + quad*4;
#pragma unroll
      for (int mi=0; mi<8; ++mi){
        int m = mb*128 + mi*16 + r16;
        size_t off = (size_t)m*NITEMS + n;
        if (n + 3 < NITEMS){
          f4a v; v.x = acc[ni2][mi][0]; v.y = acc[ni2][mi][1];
                 v.z = acc[ni2][mi][2]; v.w = acc[ni2][mi][3];
          *(f4a*)&out[off] = v;
        } else {
#pragma unroll
          for (int r=0; r<4; ++r) if (n + r < NITEMS) out[off+r] = acc[ni2][mi][r];
        }
      }
    }
  }
}

extern "C" void kernel_launch(void* const* d_in, const int* in_sizes, int n_in,
                              void* d_out, int out_size, void* d_ws, size_t ws_size,
                              hipStream_t stream){
  const float* hidden = (const float*)d_in[0];
  const int*   mask   = (const int*)d_in[1];
  const float* emb_w  = (const float*)d_in[2];
  const float* pos_w  = (const float*)d_in[3];
  const float* w1     = (const float*)d_in[4];
  const float* w2     = (const float*)d_in[5];
  const float* glu1_w = (const float*)d_in[6];
  const float* glu1_b = (const float*)d_in[7];
  const float* glu2_w = (const float*)d_in[8];
  const float* lq_w0  = (const float*)d_in[9];
  const float* lq_b0  = (const float*)d_in[10];
  const float* lq_w1  = (const float*)d_in[11];
  const float* lq_b1  = (const float*)d_in[12];
  const float* lq_w2  = (const float*)d_in[13];
  const float* lq_b2  = (const float*)d_in[14];
  const float* wz     = (const float*)d_in[15];
  const float* bz     = (const float*)d_in[16];
  const float* wo     = (const float*)d_in[17];
  const float* bo     = (const float*)d_in[18];
  const float* wt     = (const float*)d_in[19];
  const float* bt     = (const float*)d_in[20];
  const float* lt2_w  = (const float*)d_in[21];
  const float* lt2_b  = (const float*)d_in[22];
  float* outp = (float*)d_out;

  float* ws = (float*)d_ws;
  size_t o = 0;
  float* pos_part = ws + o; o += 50*128;
  float* hs       = ws + o; o += 512*128;
  float* hsg      = ws + o; o += 512*128;
  float* lastsc   = ws + o; o += 512*384;
  float* ht0v     = ws + o; o += 512*128;
  float* beta     = ws + o; o += 25600;
  float* sel      = ws + o; o += 512*128;
  float* q0f      = ws + o; o += 512*384;
  float* ais      = ws + o; o += 512*128;
  float* session  = ws + o; o += 512*128;
  unsigned short* sbf = (unsigned short*)(ws + o); o += 512*128/2;
  float* invn     = ws + o; o += 250000;
  float* big1     = ws + o; o += (size_t)25600*128;
  float* big2     = ws + o; o += (size_t)25600*128;

  k_pos_part<<<50,128,0,stream>>>(pos_w, w1, pos_part);
  k_batch_prep<<<512,128,0,stream>>>(hidden, mask, hs, lastsc, ht0v);
  k_gemmA<0><<<400,256,0,stream>>>(hidden, w1 + 128*128, pos_part, nullptr, nullptr, big1);
  k_hsg<<<512,128,0,stream>>>(hs, glu2_w, glu1_b, hsg);
  k_gemmA<1><<<400,256,0,stream>>>(big1, glu1_w, hsg, w2, mask, beta);
  k_select<<<512,128,0,stream>>>(beta, hidden, sel);
  k_hts_q0<<<512,128,0,stream>>>(lastsc, lq_w0,lq_b0,lq_w1,lq_b1,lq_w2,lq_b2, wz, bz, q0f);
  k_gemmA<2><<<400,256,0,stream>>>(hidden, wo, bo, nullptr, nullptr, big1);
  k_gemmA<2><<<400,256,0,stream>>>(hidden, wt, bt, nullptr, nullptr, big2);
  k_attn<<<512,256,0,stream>>>(q0f, big1, big2, mask, ais);
  k_session<<<512,128,0,stream>>>(ais, ht0v, sel, lt2_w, lt2_b, session, sbf);
  k_invnorm<<<62500,256,0,stream>>>(emb_w, invn);
  k_out<<<1954,256,0,stream>>>(sbf, emb_w, invn, outp);
}